// Round 14
// baseline (97.934 us; speedup 1.0000x reference)
//
#include <hip/hip_runtime.h>
#include <hip/hip_bf16.h>

#define N_GRAPHS 128
#define NODES_PER 400
#define EDGES_PER 6400
#define N_NODES (N_GRAPHS * NODES_PER)   // 51200
#define N_EDGES (N_GRAPHS * EDGES_PER)   // 819200
#define F_IN 256
#define HID 64
#define FEAT 96                          // K * 4 * D = 8*4*3
#define KTOT 352                         // 256 + 96 = 11 * 32 exactly

typedef __attribute__((ext_vector_type(8))) short bf16x8;   // MFMA A/B frag (4 VGPRs)
typedef __attribute__((ext_vector_type(4))) float f32x4;    // MFMA C/D frag

union u4b8 { uint4 u; bf16x8 v; };

// float -> bf16 RNE via scalar bit-twiddle (used off hot path)
__device__ __forceinline__ unsigned short f2b(float f) {
  union { float f; unsigned int u; } c; c.f = f;
  const unsigned int r = c.u + 0x7FFFu + ((c.u >> 16) & 1u);
  return (unsigned short)(r >> 16);
}

// packed float pair -> 2 x bf16 (v_cvt_pk_bf16_f32, RNE) — lo in low 16 bits
__device__ __forceinline__ unsigned pkbf2(float lo, float hi) {
  __hip_bfloat162 h = __float22bfloat162_rn(make_float2(lo, hi));
  return *reinterpret_cast<unsigned*>(&h);
}

// ---------------------------------------------------------------------------
// coordinate transform: one (fun, d) feature for persistence pair (x0, x1)
// ---------------------------------------------------------------------------
__device__ __forceinline__ float coord_one(
    int fun, int d, float x0, float x1,
    const float* __restrict__ t_tri, const float* __restrict__ t_gau,
    const float* __restrict__ sig, const float* __restrict__ W_lin,
    const float* __restrict__ b_lin, const float* __restrict__ c_rh,
    const float* __restrict__ r_rh) {
  if (fun == 0) {
    return fmaxf(x1 - fabsf(t_tri[d] - x0), 0.f);
  } else if (fun == 1) {
    const float dx = x0 - t_gau[d * 2 + 0];
    const float dy = x1 - t_gau[d * 2 + 1];
    const float s = sig[0];
    return expf(-(dx * dx + dy * dy) / (2.f * s * s));
  } else if (fun == 2) {
    return x0 * W_lin[d] + x1 * W_lin[3 + d] + b_lin[d];
  } else {
    const float l1 = fabsf(x0 - c_rh[d]) + fabsf(x1 - c_rh[d]);
    return 1.f / (1.f + l1) - 1.f / (1.f + fabsf(fabsf(r_rh[0]) - l1));
  }
}

// ---------------------------------------------------------------------------
// Kernel 0: chunked bf16 B operands.
//   Wt2 : (k,c) of W_out^T at [((k>>3)*256 + c)*8 + (k&7)], k < 352
//   Wt1c: (k,c) of W1^T    at [((k>>3)*64  + c)*8 + (k&7)]
// ---------------------------------------------------------------------------
__global__ __launch_bounds__(256) void k_wt(
    const float* __restrict__ W_out, const float* __restrict__ W1,
    unsigned short* __restrict__ Wt2, unsigned short* __restrict__ Wt1c) {
  const int idx = blockIdx.x * 256 + threadIdx.x;
  if (idx < KTOT * 256) {
    const int k = idx >> 8, c = idx & 255;
    Wt2[((size_t)(k >> 3) * 256 + c) * 8 + (k & 7)] = f2b(W_out[idx]);
  } else {
    const int j = idx - KTOT * 256;       // < 256*64
    const int k = j >> 6, c = j & 63;     // W1[k][c]
    Wt1c[((size_t)(k >> 3) * 64 + c) * 8 + (k & 7)] = f2b(W1[j]);
  }
}

// ---------------------------------------------------------------------------
// Kernel 1: fv = relu(relu(x @ W1 + b1) @ W2 + b2), fused with xb + ext.
// Conversions via v_cvt_pk_bf16_f32 (pkbf2).
// ---------------------------------------------------------------------------
__global__ __launch_bounds__(256, 3) void k_fv(
    const float* __restrict__ x, const unsigned short* __restrict__ Wt1c,
    const float* __restrict__ b1, const float* __restrict__ W2,
    const float* __restrict__ b2,
    const float* __restrict__ t_tri, const float* __restrict__ t_gau,
    const float* __restrict__ sig, const float* __restrict__ W_lin,
    const float* __restrict__ b_lin, const float* __restrict__ c_rh,
    const float* __restrict__ r_rh,
    float* __restrict__ fv, unsigned short* __restrict__ ext,
    unsigned short* __restrict__ xb, const int write_xb) {
  __shared__ float W2s[HID * 8];
  __shared__ float Hs[4][16][68];
  const int tid = threadIdx.x;
  const int wave = tid >> 6, lane = tid & 63;
  const int l15 = lane & 15, l4 = lane >> 4;
  const int n0 = blockIdx.x * 64;

  W2s[tid] = W2[tid];
  W2s[tid + 256] = W2[tid + 256];
  __syncthreads();

  const int arow = n0 + wave * 16 + l15;
  bf16x8 afr[8];
  #pragma unroll
  for (int kt = 0; kt < 8; ++kt) {
    const size_t go = (size_t)arow * F_IN + kt * 32 + l4 * 8;
    const float4 f0 = *(const float4*)&x[go];
    const float4 f1 = *(const float4*)&x[go + 4];
    u4b8 w;
    w.u.x = pkbf2(f0.x, f0.y);
    w.u.y = pkbf2(f0.z, f0.w);
    w.u.z = pkbf2(f1.x, f1.y);
    w.u.w = pkbf2(f1.z, f1.w);
    if (write_xb) *(uint4*)&xb[go] = w.u;
    afr[kt] = w.v;
  }

  f32x4 acc[4];
  #pragma unroll
  for (int nf = 0; nf < 4; ++nf) acc[nf] = (f32x4){0.f, 0.f, 0.f, 0.f};
  #pragma unroll
  for (int kt = 0; kt < 8; ++kt) {
    const unsigned short* wb = Wt1c + (size_t)(kt * 4 + l4) * 512;
    #pragma unroll
    for (int nf = 0; nf < 4; ++nf) {
      const bf16x8 b = *(const bf16x8*)&wb[(nf * 16 + l15) * 8];
      acc[nf] = __builtin_amdgcn_mfma_f32_16x16x32_bf16(afr[kt], b, acc[nf], 0, 0, 0);
    }
  }

  #pragma unroll
  for (int nf = 0; nf < 4; ++nf) {
    const int col = nf * 16 + l15;
    const float bb = b1[col];
    #pragma unroll
    for (int j = 0; j < 4; ++j)
      Hs[wave][l4 * 4 + j][col] = fmaxf(acc[nf][j] + bb, 0.f);
  }
  __syncthreads();

  #pragma unroll
  for (int p = tid; p < 512; p += 256) {
    const int row = p >> 3, kk = p & 7;
    const float* hr = Hs[row >> 4][row & 15];
    float s = b2[kk];
    #pragma unroll 8
    for (int j = 0; j < HID; ++j) s = fmaf(hr[j], W2s[j * 8 + kk], s);
    s = fmaxf(s, 0.f);
    const int n = n0 + row;
    fv[(size_t)n * 8 + kk] = s;

    float fo[12];
    #pragma unroll
    for (int fun = 0; fun < 4; ++fun)
      #pragma unroll
      for (int d = 0; d < 3; ++d)
        fo[fun * 3 + d] = coord_one(fun, d, s, s,
                                    t_tri, t_gau, sig, W_lin, b_lin, c_rh, r_rh);
    unsigned o32[6];
    #pragma unroll
    for (int i = 0; i < 6; ++i) o32[i] = pkbf2(fo[2 * i], fo[2 * i + 1]);
    unsigned short* dst = &ext[(size_t)n * FEAT + kk * 12];  // 8B-aligned
    *(uint2*)&dst[0] = make_uint2(o32[0], o32[1]);
    *(uint2*)&dst[4] = make_uint2(o32[2], o32[3]);
    *(uint2*)&dst[8] = make_uint2(o32[4], o32[5]);
  }
}

// ---------------------------------------------------------------------------
// Kernel 2: per-chunk partial max -> unpP[g][ch][k]; unconditional write,
// no pre-zero, no atomics.
// ---------------------------------------------------------------------------
#define CHUNK (EDGES_PER / 8)   // 800
__global__ __launch_bounds__(256) void k_unpaired(
    const int* __restrict__ ei, const float* __restrict__ fv,
    float* __restrict__ unpP) {
  __shared__ float lfv[NODES_PER * 8];
  __shared__ float red[256][8];
  const int g = blockIdx.x >> 3, ch = blockIdx.x & 7;
  const int tid = threadIdx.x;

  for (int i = tid; i < NODES_PER * 2; i += 256)
    *(float4*)&lfv[i * 4] = *(const float4*)&fv[(size_t)g * NODES_PER * 8 + i * 4];
  __syncthreads();

  float lm[8];
  #pragma unroll
  for (int k = 0; k < 8; ++k) lm[k] = 0.f;
  const int e0 = g * EDGES_PER + ch * CHUNK;
  for (int e = e0 + tid; e < e0 + CHUNK; e += 256) {
    const int a = ei[e] - g * NODES_PER;
    const int b = ei[N_EDGES + e] - g * NODES_PER;
    const float4 a0 = *(const float4*)&lfv[a * 8];
    const float4 a1 = *(const float4*)&lfv[a * 8 + 4];
    const float4 b0 = *(const float4*)&lfv[b * 8];
    const float4 b1 = *(const float4*)&lfv[b * 8 + 4];
    lm[0] = fmaxf(lm[0], fmaxf(a0.x, b0.x));
    lm[1] = fmaxf(lm[1], fmaxf(a0.y, b0.y));
    lm[2] = fmaxf(lm[2], fmaxf(a0.z, b0.z));
    lm[3] = fmaxf(lm[3], fmaxf(a0.w, b0.w));
    lm[4] = fmaxf(lm[4], fmaxf(a1.x, b1.x));
    lm[5] = fmaxf(lm[5], fmaxf(a1.y, b1.y));
    lm[6] = fmaxf(lm[6], fmaxf(a1.z, b1.z));
    lm[7] = fmaxf(lm[7], fmaxf(a1.w, b1.w));
  }
  #pragma unroll
  for (int k = 0; k < 8; ++k) red[tid][k] = lm[k];
  __syncthreads();
  for (int s = 128; s > 0; s >>= 1) {
    if (tid < s) {
      #pragma unroll
      for (int k = 0; k < 8; ++k)
        red[tid][k] = fmaxf(red[tid][k], red[tid + s][k]);
    }
    __syncthreads();
  }
  if (tid < 8) unpP[(size_t)(g * 8 + ch) * 8 + tid] = red[0][tid];
}

// ---------------------------------------------------------------------------
// Kernel 3: reduce unpP chunks -> u[k]; G[g][c] = b_out[c] +
//           sum_t feat1[g][t] * W_out[352+t][c]   (g1 segment fold, fp32)
// ---------------------------------------------------------------------------
__global__ __launch_bounds__(256) void k_g1G(
    const float* __restrict__ unpP, const float* __restrict__ t_tri,
    const float* __restrict__ t_gau, const float* __restrict__ sig,
    const float* __restrict__ W_lin, const float* __restrict__ b_lin,
    const float* __restrict__ c_rh, const float* __restrict__ r_rh,
    const float* __restrict__ W_out, const float* __restrict__ b_out,
    float* __restrict__ G) {
  const int g = blockIdx.x;
  const int t = threadIdx.x;  // 0..255
  __shared__ float u[8];
  __shared__ float feat[96];
  if (t < 8) {
    float m = 0.f;
    #pragma unroll
    for (int ch = 0; ch < 8; ++ch)
      m = fmaxf(m, unpP[(size_t)(g * 8 + ch) * 8 + t]);
    u[t] = m;
  }
  __syncthreads();
  if (t < 96) {
    const float mask = (u[0] != 0.f || u[1] != 0.f || u[2] != 0.f ||
                        u[3] != 0.f || u[4] != 0.f || u[5] != 0.f ||
                        u[6] != 0.f || u[7] != 0.f) ? 1.f : 0.f;
    const int k = t / 12;
    const int fun = (t % 12) / 3;
    const int d = t % 3;
    feat[t] = mask * coord_one(fun, d, u[k], 0.f,
                               t_tri, t_gau, sig, W_lin, b_lin, c_rh, r_rh);
  }
  __syncthreads();
  float s = b_out[t];
  #pragma unroll 4
  for (int f = 0; f < 96; ++f)
    s = fmaf(feat[f], W_out[(size_t)(352 + f) * 256 + t], s);
  G[g * 256 + t] = s;
}

// ---------------------------------------------------------------------------
// Kernel 4: out = relu([x|act0] @ W_out[0:352] + G[batch])  via MFMA.
// BARRIER-FREE, LDS-FREE, B-IN-REGISTERS at 3 waves/SIMD:
//   1024 blocks x 4 waves; fam = blockIdx&1 picks col half; wave owns a
//   32-col slice -> B = 22 frags = 88 VGPR, held as uint4 and PINNED with
//   asm "+v" (value no longer provably equal to memory -> allocator cannot
//   rematerialize it from Wt2; the round-10 cliff is structurally excluded).
//   __launch_bounds__(256,3) -> 168-VGPR ceiling, demand ~155 incl. held A.
//   Blocks walk 16-row tiles (stride 512); both fams read the same A rows
//   (L3-served). No barriers after B load; 12 waves/CU hide A latency.
// ---------------------------------------------------------------------------
__global__ __launch_bounds__(256, 3) void k_out_mfma(
    const float* __restrict__ x, const unsigned short* __restrict__ xb,
    const unsigned short* __restrict__ ext,
    const unsigned short* __restrict__ Wt2, const float* __restrict__ G,
    float* __restrict__ out, const int use_xb) {
  const int tid = threadIdx.x;
  const int wave = tid >> 6, lane = tid & 63;
  const int l15 = lane & 15, l4 = lane >> 4;
  const int fam = blockIdx.x & 1;
  const int c0 = fam * 128 + wave * 32;     // 32-col slice of this wave

  // ---- persistent B slice: 22 frags (ks 0..10 x nf 0..1), 88 VGPR, pinned
  uint4 bu[11][2];
  #pragma unroll
  for (int ks = 0; ks < 11; ++ks)
    #pragma unroll
    for (int nf = 0; nf < 2; ++nf) {
      bu[ks][nf] = *(const uint4*)
          &Wt2[((size_t)(ks * 4 + l4) * 256 + c0 + nf * 16 + l15) * 8];
      asm volatile("" : "+v"(bu[ks][nf].x), "+v"(bu[ks][nf].y),
                        "+v"(bu[ks][nf].z), "+v"(bu[ks][nf].w));
    }

  for (int t = blockIdx.x >> 1; t < N_NODES / 16; t += 512) {
    const int arow = t * 16 + l15;
    const int gidx = t / 25;                // 400 = 25*16: graph of this tile

    // ---- A frags: 11 contiguous 16B loads (x | ext segments) ----
    bf16x8 a[11];
    if (use_xb) {
      #pragma unroll
      for (int ks = 0; ks < 8; ++ks)
        a[ks] = *(const bf16x8*)&xb[(size_t)arow * F_IN + ks * 32 + l4 * 8];
    } else {
      #pragma unroll
      for (int ks = 0; ks < 8; ++ks) {
        const size_t go = (size_t)arow * F_IN + ks * 32 + l4 * 8;
        const float4 f0 = *(const float4*)&x[go];
        const float4 f1 = *(const float4*)&x[go + 4];
        u4b8 w;
        w.u.x = pkbf2(f0.x, f0.y);
        w.u.y = pkbf2(f0.z, f0.w);
        w.u.z = pkbf2(f1.x, f1.y);
        w.u.w = pkbf2(f1.z, f1.w);
        a[ks] = w.v;
      }
    }
    #pragma unroll
    for (int ks = 8; ks < 11; ++ks)
      a[ks] = *(const bf16x8*)&ext[(size_t)arow * FEAT + (ks - 8) * 32 + l4 * 8];

    // ---- 22 MFMA ----
    f32x4 acc[2];
    acc[0] = (f32x4){0.f, 0.f, 0.f, 0.f};
    acc[1] = (f32x4){0.f, 0.f, 0.f, 0.f};
    #pragma unroll
    for (int ks = 0; ks < 11; ++ks) {
      #pragma unroll
      for (int nf = 0; nf < 2; ++nf) {
        const bf16x8 b = ((const u4b8*)&bu[ks][nf])->v;
        acc[nf] = __builtin_amdgcn_mfma_f32_16x16x32_bf16(a[ks], b, acc[nf], 0, 0, 0);
      }
    }

    // ---- epilogue: + G[graph] (bias + g1 fold), relu, store ----
    #pragma unroll
    for (int nf = 0; nf < 2; ++nf) {
      const int col = c0 + nf * 16 + l15;
      const float gv = G[gidx * 256 + col];
      #pragma unroll
      for (int j = 0; j < 4; ++j) {
        const int row = t * 16 + l4 * 4 + j;
        out[(size_t)row * 256 + col] = fmaxf(acc[nf][j] + gv, 0.f);
      }
    }
  }
}

// ---------------------------------------------------------------------------
extern "C" void kernel_launch(void* const* d_in, const int* in_sizes, int n_in,
                              void* d_out, int out_size, void* d_ws, size_t ws_size,
                              hipStream_t stream) {
  const float* x          = (const float*)d_in[0];
  const int*   edge_index = (const int*)d_in[1];
  // d_in[2] = batch_vec (row/400 computed inline), d_in[3] = edge_slices: unused
  const float* W1     = (const float*)d_in[4];
  const float* b1     = (const float*)d_in[5];
  const float* W2     = (const float*)d_in[6];
  const float* b2     = (const float*)d_in[7];
  const float* t_tri0 = (const float*)d_in[8];
  const float* t_gau0 = (const float*)d_in[9];
  const float* sig0   = (const float*)d_in[10];
  const float* W_lin0 = (const float*)d_in[11];
  const float* b_lin0 = (const float*)d_in[12];
  const float* c_rh0  = (const float*)d_in[13];
  const float* r_rh0  = (const float*)d_in[14];
  const float* t_tri1 = (const float*)d_in[15];
  const float* t_gau1 = (const float*)d_in[16];
  const float* sig1   = (const float*)d_in[17];
  const float* W_lin1 = (const float*)d_in[18];
  const float* b_lin1 = (const float*)d_in[19];
  const float* c_rh1  = (const float*)d_in[20];
  const float* r_rh1  = (const float*)d_in[21];
  const float* W_out  = (const float*)d_in[22];
  const float* b_out  = (const float*)d_in[23];
  float* out = (float*)d_out;

  // workspace layout (16B-aligned):
  // fv 1.6M | unpP 32K | G 128K | Wt2 176K | Wt1c 32K | ext 9.8M | xb 26M
  char* base = (char*)d_ws;
  float* fv            = (float*)(base + 0);
  float* unpP          = (float*)(base + 1638400);
  float* G             = (float*)(base + 1671168);
  unsigned short* Wt2  = (unsigned short*)(base + 1802240);
  unsigned short* Wt1c = (unsigned short*)(base + 1982464);
  unsigned short* ext  = (unsigned short*)(base + 2015232);
  unsigned short* xb   = (unsigned short*)(base + 11845632);
  const size_t ws_need_xb = 11845632 + (size_t)N_NODES * F_IN * 2;  // ~38 MB
  const int use_xb = ws_size >= ws_need_xb ? 1 : 0;

  k_wt<<<(KTOT * 256 + F_IN * HID) / 256, 256, 0, stream>>>(W_out, W1, Wt2, Wt1c);
  k_fv<<<N_NODES / 64, 256, 0, stream>>>(
      x, Wt1c, b1, W2, b2,
      t_tri0, t_gau0, sig0, W_lin0, b_lin0, c_rh0, r_rh0,
      fv, ext, xb, use_xb);
  k_unpaired<<<N_GRAPHS * 8, 256, 0, stream>>>(edge_index, fv, unpP);
  k_g1G<<<N_GRAPHS, 256, 0, stream>>>(unpP, t_tri1, t_gau1, sig1,
                                      W_lin1, b_lin1, c_rh1, r_rh1,
                                      W_out, b_out, G);
  k_out_mfma<<<1024, 256, 0, stream>>>(x, xb, ext, Wt2, G, out, use_xb);
}

// Round 15
// 73.187 us; speedup vs baseline: 1.3381x; 1.3381x over previous
//
#include <hip/hip_runtime.h>
#include <hip/hip_bf16.h>

#define N_GRAPHS 128
#define NODES_PER 400
#define EDGES_PER 6400
#define N_NODES (N_GRAPHS * NODES_PER)   // 51200
#define N_EDGES (N_GRAPHS * EDGES_PER)   // 819200
#define F_IN 256
#define HID 64
#define FEAT 96                          // K * 4 * D = 8*4*3
#define KTOT 352                         // 256 + 96 = 11 * 32 exactly

typedef __attribute__((ext_vector_type(8))) short bf16x8;   // MFMA A/B frag (4 VGPRs)
typedef __attribute__((ext_vector_type(4))) float f32x4;    // MFMA C/D frag

union u4b8 { uint4 u; bf16x8 v; };

// float -> bf16 RNE via scalar bit-twiddle (used off hot path)
__device__ __forceinline__ unsigned short f2b(float f) {
  union { float f; unsigned int u; } c; c.f = f;
  const unsigned int r = c.u + 0x7FFFu + ((c.u >> 16) & 1u);
  return (unsigned short)(r >> 16);
}

// packed float pair -> 2 x bf16 (v_cvt_pk_bf16_f32, RNE) — lo in low 16 bits
__device__ __forceinline__ unsigned pkbf2(float lo, float hi) {
  __hip_bfloat162 h = __float22bfloat162_rn(make_float2(lo, hi));
  return *reinterpret_cast<unsigned*>(&h);
}

// ---------------------------------------------------------------------------
// coordinate transform: one (fun, d) feature for persistence pair (x0, x1)
// ---------------------------------------------------------------------------
__device__ __forceinline__ float coord_one(
    int fun, int d, float x0, float x1,
    const float* __restrict__ t_tri, const float* __restrict__ t_gau,
    const float* __restrict__ sig, const float* __restrict__ W_lin,
    const float* __restrict__ b_lin, const float* __restrict__ c_rh,
    const float* __restrict__ r_rh) {
  if (fun == 0) {
    return fmaxf(x1 - fabsf(t_tri[d] - x0), 0.f);
  } else if (fun == 1) {
    const float dx = x0 - t_gau[d * 2 + 0];
    const float dy = x1 - t_gau[d * 2 + 1];
    const float s = sig[0];
    return expf(-(dx * dx + dy * dy) / (2.f * s * s));
  } else if (fun == 2) {
    return x0 * W_lin[d] + x1 * W_lin[3 + d] + b_lin[d];
  } else {
    const float l1 = fabsf(x0 - c_rh[d]) + fabsf(x1 - c_rh[d]);
    return 1.f / (1.f + l1) - 1.f / (1.f + fabsf(fabsf(r_rh[0]) - l1));
  }
}

// ---------------------------------------------------------------------------
// Kernel 0: chunked bf16 B operands.
//   Wt2 : (k,c) of W_out^T at [((k>>3)*256 + c)*8 + (k&7)], k < 352
//   Wt1c: (k,c) of W1^T    at [((k>>3)*64  + c)*8 + (k&7)]
// ---------------------------------------------------------------------------
__global__ __launch_bounds__(256) void k_wt(
    const float* __restrict__ W_out, const float* __restrict__ W1,
    unsigned short* __restrict__ Wt2, unsigned short* __restrict__ Wt1c) {
  const int idx = blockIdx.x * 256 + threadIdx.x;
  if (idx < KTOT * 256) {
    const int k = idx >> 8, c = idx & 255;
    Wt2[((size_t)(k >> 3) * 256 + c) * 8 + (k & 7)] = f2b(W_out[idx]);
  } else {
    const int j = idx - KTOT * 256;       // < 256*64
    const int k = j >> 6, c = j & 63;     // W1[k][c]
    Wt1c[((size_t)(k >> 3) * 64 + c) * 8 + (k & 7)] = f2b(W1[j]);
  }
}

// ---------------------------------------------------------------------------
// Kernel 1: fv = relu(relu(x @ W1 + b1) @ W2 + b2), fused with xb + ext.
// Conversions via v_cvt_pk_bf16_f32 (pkbf2).
// ---------------------------------------------------------------------------
__global__ __launch_bounds__(256, 3) void k_fv(
    const float* __restrict__ x, const unsigned short* __restrict__ Wt1c,
    const float* __restrict__ b1, const float* __restrict__ W2,
    const float* __restrict__ b2,
    const float* __restrict__ t_tri, const float* __restrict__ t_gau,
    const float* __restrict__ sig, const float* __restrict__ W_lin,
    const float* __restrict__ b_lin, const float* __restrict__ c_rh,
    const float* __restrict__ r_rh,
    float* __restrict__ fv, unsigned short* __restrict__ ext,
    unsigned short* __restrict__ xb, const int write_xb) {
  __shared__ float W2s[HID * 8];
  __shared__ float Hs[4][16][68];
  const int tid = threadIdx.x;
  const int wave = tid >> 6, lane = tid & 63;
  const int l15 = lane & 15, l4 = lane >> 4;
  const int n0 = blockIdx.x * 64;

  W2s[tid] = W2[tid];
  W2s[tid + 256] = W2[tid + 256];
  __syncthreads();

  const int arow = n0 + wave * 16 + l15;
  bf16x8 afr[8];
  #pragma unroll
  for (int kt = 0; kt < 8; ++kt) {
    const size_t go = (size_t)arow * F_IN + kt * 32 + l4 * 8;
    const float4 f0 = *(const float4*)&x[go];
    const float4 f1 = *(const float4*)&x[go + 4];
    u4b8 w;
    w.u.x = pkbf2(f0.x, f0.y);
    w.u.y = pkbf2(f0.z, f0.w);
    w.u.z = pkbf2(f1.x, f1.y);
    w.u.w = pkbf2(f1.z, f1.w);
    if (write_xb) *(uint4*)&xb[go] = w.u;
    afr[kt] = w.v;
  }

  f32x4 acc[4];
  #pragma unroll
  for (int nf = 0; nf < 4; ++nf) acc[nf] = (f32x4){0.f, 0.f, 0.f, 0.f};
  #pragma unroll
  for (int kt = 0; kt < 8; ++kt) {
    const unsigned short* wb = Wt1c + (size_t)(kt * 4 + l4) * 512;
    #pragma unroll
    for (int nf = 0; nf < 4; ++nf) {
      const bf16x8 b = *(const bf16x8*)&wb[(nf * 16 + l15) * 8];
      acc[nf] = __builtin_amdgcn_mfma_f32_16x16x32_bf16(afr[kt], b, acc[nf], 0, 0, 0);
    }
  }

  #pragma unroll
  for (int nf = 0; nf < 4; ++nf) {
    const int col = nf * 16 + l15;
    const float bb = b1[col];
    #pragma unroll
    for (int j = 0; j < 4; ++j)
      Hs[wave][l4 * 4 + j][col] = fmaxf(acc[nf][j] + bb, 0.f);
  }
  __syncthreads();

  #pragma unroll
  for (int p = tid; p < 512; p += 256) {
    const int row = p >> 3, kk = p & 7;
    const float* hr = Hs[row >> 4][row & 15];
    float s = b2[kk];
    #pragma unroll 8
    for (int j = 0; j < HID; ++j) s = fmaf(hr[j], W2s[j * 8 + kk], s);
    s = fmaxf(s, 0.f);
    const int n = n0 + row;
    fv[(size_t)n * 8 + kk] = s;

    float fo[12];
    #pragma unroll
    for (int fun = 0; fun < 4; ++fun)
      #pragma unroll
      for (int d = 0; d < 3; ++d)
        fo[fun * 3 + d] = coord_one(fun, d, s, s,
                                    t_tri, t_gau, sig, W_lin, b_lin, c_rh, r_rh);
    unsigned o32[6];
    #pragma unroll
    for (int i = 0; i < 6; ++i) o32[i] = pkbf2(fo[2 * i], fo[2 * i + 1]);
    unsigned short* dst = &ext[(size_t)n * FEAT + kk * 12];  // 8B-aligned
    *(uint2*)&dst[0] = make_uint2(o32[0], o32[1]);
    *(uint2*)&dst[4] = make_uint2(o32[2], o32[3]);
    *(uint2*)&dst[8] = make_uint2(o32[4], o32[5]);
  }
}

// ---------------------------------------------------------------------------
// Kernel 2: per-chunk partial max -> unpP[g][ch][k]; unconditional write,
// no pre-zero, no atomics.
// ---------------------------------------------------------------------------
#define CHUNK (EDGES_PER / 8)   // 800
__global__ __launch_bounds__(256) void k_unpaired(
    const int* __restrict__ ei, const float* __restrict__ fv,
    float* __restrict__ unpP) {
  __shared__ float lfv[NODES_PER * 8];
  __shared__ float red[256][8];
  const int g = blockIdx.x >> 3, ch = blockIdx.x & 7;
  const int tid = threadIdx.x;

  for (int i = tid; i < NODES_PER * 2; i += 256)
    *(float4*)&lfv[i * 4] = *(const float4*)&fv[(size_t)g * NODES_PER * 8 + i * 4];
  __syncthreads();

  float lm[8];
  #pragma unroll
  for (int k = 0; k < 8; ++k) lm[k] = 0.f;
  const int e0 = g * EDGES_PER + ch * CHUNK;
  for (int e = e0 + tid; e < e0 + CHUNK; e += 256) {
    const int a = ei[e] - g * NODES_PER;
    const int b = ei[N_EDGES + e] - g * NODES_PER;
    const float4 a0 = *(const float4*)&lfv[a * 8];
    const float4 a1 = *(const float4*)&lfv[a * 8 + 4];
    const float4 b0 = *(const float4*)&lfv[b * 8];
    const float4 b1 = *(const float4*)&lfv[b * 8 + 4];
    lm[0] = fmaxf(lm[0], fmaxf(a0.x, b0.x));
    lm[1] = fmaxf(lm[1], fmaxf(a0.y, b0.y));
    lm[2] = fmaxf(lm[2], fmaxf(a0.z, b0.z));
    lm[3] = fmaxf(lm[3], fmaxf(a0.w, b0.w));
    lm[4] = fmaxf(lm[4], fmaxf(a1.x, b1.x));
    lm[5] = fmaxf(lm[5], fmaxf(a1.y, b1.y));
    lm[6] = fmaxf(lm[6], fmaxf(a1.z, b1.z));
    lm[7] = fmaxf(lm[7], fmaxf(a1.w, b1.w));
  }
  #pragma unroll
  for (int k = 0; k < 8; ++k) red[tid][k] = lm[k];
  __syncthreads();
  for (int s = 128; s > 0; s >>= 1) {
    if (tid < s) {
      #pragma unroll
      for (int k = 0; k < 8; ++k)
        red[tid][k] = fmaxf(red[tid][k], red[tid + s][k]);
    }
    __syncthreads();
  }
  if (tid < 8) unpP[(size_t)(g * 8 + ch) * 8 + tid] = red[0][tid];
}

// ---------------------------------------------------------------------------
// Kernel 3: reduce unpP chunks -> u[k]; G[g][c] = b_out[c] +
//           sum_t feat1[g][t] * W_out[352+t][c]   (g1 segment fold, fp32)
// ---------------------------------------------------------------------------
__global__ __launch_bounds__(256) void k_g1G(
    const float* __restrict__ unpP, const float* __restrict__ t_tri,
    const float* __restrict__ t_gau, const float* __restrict__ sig,
    const float* __restrict__ W_lin, const float* __restrict__ b_lin,
    const float* __restrict__ c_rh, const float* __restrict__ r_rh,
    const float* __restrict__ W_out, const float* __restrict__ b_out,
    float* __restrict__ G) {
  const int g = blockIdx.x;
  const int t = threadIdx.x;  // 0..255
  __shared__ float u[8];
  __shared__ float feat[96];
  if (t < 8) {
    float m = 0.f;
    #pragma unroll
    for (int ch = 0; ch < 8; ++ch)
      m = fmaxf(m, unpP[(size_t)(g * 8 + ch) * 8 + t]);
    u[t] = m;
  }
  __syncthreads();
  if (t < 96) {
    const float mask = (u[0] != 0.f || u[1] != 0.f || u[2] != 0.f ||
                        u[3] != 0.f || u[4] != 0.f || u[5] != 0.f ||
                        u[6] != 0.f || u[7] != 0.f) ? 1.f : 0.f;
    const int k = t / 12;
    const int fun = (t % 12) / 3;
    const int d = t % 3;
    feat[t] = mask * coord_one(fun, d, u[k], 0.f,
                               t_tri, t_gau, sig, W_lin, b_lin, c_rh, r_rh);
  }
  __syncthreads();
  float s = b_out[t];
  #pragma unroll 4
  for (int f = 0; f < 96; ++f)
    s = fmaf(feat[f], W_out[(size_t)(352 + f) * 256 + t], s);
  G[g * 256 + t] = s;
}

// ---------------------------------------------------------------------------
// Kernel 4: out = relu([x|act0] @ W_out[0:352] + G[batch])  via MFMA.
// BARRIER-FREE, LDS-FREE, B-IN-REGISTERS (round-8/9/13 structure — the
// measured best at ~31 us; rounds 10/11/12/14 alternatives each tripped a
// different allocator cliff: remat at 128-VGPR ceiling / clobber-serialized
// loop / lambda-array scratch spill / pin-forced scratch spill. 176-VGPR
// persistent B at 2 waves/SIMD is the allocator-stable point):
//   512 blocks x 4 waves; wave w owns col-quarter w with its full B-slice
//   (44 bf16x8 = 176 VGPR) loaded once; grid-stride over 16-row tiles.
// ---------------------------------------------------------------------------
__global__ __launch_bounds__(256, 2) void k_out_mfma(
    const float* __restrict__ x, const unsigned short* __restrict__ xb,
    const unsigned short* __restrict__ ext,
    const unsigned short* __restrict__ Wt2, const float* __restrict__ G,
    float* __restrict__ out, const int use_xb) {
  const int tid = threadIdx.x;
  const int wave = tid >> 6, lane = tid & 63;
  const int l15 = lane & 15, l4 = lane >> 4;
  const int q = wave;                       // col-quarter owned by this wave

  // ---- load persistent B slice: 44 frags (ks 0..10 x nf 0..3) ----
  bf16x8 b[11][4];
  #pragma unroll
  for (int ks = 0; ks < 11; ++ks)
    #pragma unroll
    for (int nf = 0; nf < 4; ++nf)
      b[ks][nf] = *(const bf16x8*)
          &Wt2[((size_t)(ks * 4 + l4) * 256 + q * 64 + nf * 16 + l15) * 8];

  for (int t = blockIdx.x; t < N_NODES / 16; t += gridDim.x) {
    const int arow = t * 16 + l15;
    const int gidx = t / 25;                // 400 = 25*16: graph of this tile

    // ---- A frags: 11 contiguous 16B loads (x | ext segments) ----
    bf16x8 a[11];
    if (use_xb) {
      #pragma unroll
      for (int ks = 0; ks < 8; ++ks)
        a[ks] = *(const bf16x8*)&xb[(size_t)arow * F_IN + ks * 32 + l4 * 8];
    } else {
      #pragma unroll
      for (int ks = 0; ks < 8; ++ks) {
        const size_t go = (size_t)arow * F_IN + ks * 32 + l4 * 8;
        const float4 f0 = *(const float4*)&x[go];
        const float4 f1 = *(const float4*)&x[go + 4];
        u4b8 w;
        w.u.x = pkbf2(f0.x, f0.y);
        w.u.y = pkbf2(f0.z, f0.w);
        w.u.z = pkbf2(f1.x, f1.y);
        w.u.w = pkbf2(f1.z, f1.w);
        a[ks] = w.v;
      }
    }
    #pragma unroll
    for (int ks = 8; ks < 11; ++ks)
      a[ks] = *(const bf16x8*)&ext[(size_t)arow * FEAT + (ks - 8) * 32 + l4 * 8];

    // ---- 44 MFMA ----
    f32x4 acc[4];
    #pragma unroll
    for (int nf = 0; nf < 4; ++nf) acc[nf] = (f32x4){0.f, 0.f, 0.f, 0.f};
    #pragma unroll
    for (int ks = 0; ks < 11; ++ks)
      #pragma unroll
      for (int nf = 0; nf < 4; ++nf)
        acc[nf] = __builtin_amdgcn_mfma_f32_16x16x32_bf16(
            a[ks], b[ks][nf], acc[nf], 0, 0, 0);

    // ---- epilogue: + G[graph] (bias + g1 fold), relu, store ----
    #pragma unroll
    for (int nf = 0; nf < 4; ++nf) {
      const int col = q * 64 + nf * 16 + l15;
      const float gv = G[gidx * 256 + col];
      #pragma unroll
      for (int j = 0; j < 4; ++j) {
        const int row = t * 16 + l4 * 4 + j;
        out[(size_t)row * 256 + col] = fmaxf(acc[nf][j] + gv, 0.f);
      }
    }
  }
}

// ---------------------------------------------------------------------------
extern "C" void kernel_launch(void* const* d_in, const int* in_sizes, int n_in,
                              void* d_out, int out_size, void* d_ws, size_t ws_size,
                              hipStream_t stream) {
  const float* x          = (const float*)d_in[0];
  const int*   edge_index = (const int*)d_in[1];
  // d_in[2] = batch_vec (row/400 computed inline), d_in[3] = edge_slices: unused
  const float* W1     = (const float*)d_in[4];
  const float* b1     = (const float*)d_in[5];
  const float* W2     = (const float*)d_in[6];
  const float* b2     = (const float*)d_in[7];
  const float* t_tri0 = (const float*)d_in[8];
  const float* t_gau0 = (const float*)d_in[9];
  const float* sig0   = (const float*)d_in[10];
  const float* W_lin0 = (const float*)d_in[11];
  const float* b_lin0 = (const float*)d_in[12];
  const float* c_rh0  = (const float*)d_in[13];
  const float* r_rh0  = (const float*)d_in[14];
  const float* t_tri1 = (const float*)d_in[15];
  const float* t_gau1 = (const float*)d_in[16];
  const float* sig1   = (const float*)d_in[17];
  const float* W_lin1 = (const float*)d_in[18];
  const float* b_lin1 = (const float*)d_in[19];
  const float* c_rh1  = (const float*)d_in[20];
  const float* r_rh1  = (const float*)d_in[21];
  const float* W_out  = (const float*)d_in[22];
  const float* b_out  = (const float*)d_in[23];
  float* out = (float*)d_out;

  // workspace layout (16B-aligned):
  // fv 1.6M | unpP 32K | G 128K | Wt2 176K | Wt1c 32K | ext 9.8M | xb 26M
  char* base = (char*)d_ws;
  float* fv            = (float*)(base + 0);
  float* unpP          = (float*)(base + 1638400);
  float* G             = (float*)(base + 1671168);
  unsigned short* Wt2  = (unsigned short*)(base + 1802240);
  unsigned short* Wt1c = (unsigned short*)(base + 1982464);
  unsigned short* ext  = (unsigned short*)(base + 2015232);
  unsigned short* xb   = (unsigned short*)(base + 11845632);
  const size_t ws_need_xb = 11845632 + (size_t)N_NODES * F_IN * 2;  // ~38 MB
  const int use_xb = ws_size >= ws_need_xb ? 1 : 0;

  k_wt<<<(KTOT * 256 + F_IN * HID) / 256, 256, 0, stream>>>(W_out, W1, Wt2, Wt1c);
  k_fv<<<N_NODES / 64, 256, 0, stream>>>(
      x, Wt1c, b1, W2, b2,
      t_tri0, t_gau0, sig0, W_lin0, b_lin0, c_rh0, r_rh0,
      fv, ext, xb, use_xb);
  k_unpaired<<<N_GRAPHS * 8, 256, 0, stream>>>(edge_index, fv, unpP);
  k_g1G<<<N_GRAPHS, 256, 0, stream>>>(unpP, t_tri1, t_gau1, sig1,
                                      W_lin1, b_lin1, c_rh1, r_rh1,
                                      W_out, b_out, G);
  k_out_mfma<<<512, 256, 0, stream>>>(x, xb, ext, Wt2, G, out, use_xb);
}